// Round 5
// baseline (689.389 us; speedup 1.0000x reference)
//
#include <hip/hip_runtime.h>

#define N_NODES 100000
#define N_EDGES 1200000
#define LAYERS 4
#define SLOPE 0.01f

#define SCAN_ELEMS 1024                      // elems per scan1 block (256 thr x 4)
#define NB1 ((N_NODES + SCAN_ELEMS - 1) / SCAN_ELEMS)   // 98

__device__ __forceinline__ float leaky(float v) { return v >= 0.f ? v : SLOPE * v; }

// ---------------------------------------------------------------------------
// CSR build (counting sort by edge_dst) — runs once per launch
// ---------------------------------------------------------------------------
__global__ __launch_bounds__(256) void zero_counts(int* __restrict__ counts)
{
    int i = blockIdx.x * 256 + threadIdx.x;
    if (i < N_NODES) counts[i] = 0;
}

__global__ __launch_bounds__(256) void count_kernel(
    const int* __restrict__ dst, int* __restrict__ counts)
{
    int e = blockIdx.x * 256 + threadIdx.x;
    if (e < N_EDGES) atomicAdd(&counts[dst[e]], 1);
}

__global__ __launch_bounds__(256) void scan1_kernel(
    const int* __restrict__ counts, int* __restrict__ offs, int* __restrict__ bsum)
{
    __shared__ int s[256];
    int b = blockIdx.x, t = threadIdx.x;
    int base = b * SCAN_ELEMS;
    int v[4]; int sum = 0;
    #pragma unroll
    for (int u = 0; u < 4; u++) {
        int idx = base + t * 4 + u;
        int c = (idx < N_NODES) ? counts[idx] : 0;
        v[u] = sum; sum += c;
    }
    s[t] = sum; __syncthreads();
    for (int off = 1; off < 256; off <<= 1) {
        int y = (t >= off) ? s[t - off] : 0;
        __syncthreads();
        s[t] += y;
        __syncthreads();
    }
    int excl = s[t] - sum;
    #pragma unroll
    for (int u = 0; u < 4; u++) {
        int idx = base + t * 4 + u;
        if (idx < N_NODES) offs[idx] = excl + v[u];
    }
    if (t == 255) bsum[b] = s[255];
}

__global__ __launch_bounds__(128) void scan2_kernel(
    const int* __restrict__ bsum, int* __restrict__ bscan)
{
    __shared__ int s[128];
    int t = threadIdx.x;
    int c = (t < NB1) ? bsum[t] : 0;
    s[t] = c; __syncthreads();
    for (int off = 1; off < 128; off <<= 1) {
        int y = (t >= off) ? s[t - off] : 0;
        __syncthreads();
        s[t] += y;
        __syncthreads();
    }
    if (t < NB1) bscan[t] = s[t] - c;
}

__global__ __launch_bounds__(256) void scan3_kernel(
    int* __restrict__ offs, int* __restrict__ cursor, const int* __restrict__ bscan)
{
    int b = blockIdx.x, t = threadIdx.x;
    int base = b * SCAN_ELEMS;
    int add = bscan[b];
    #pragma unroll
    for (int u = 0; u < 4; u++) {
        int idx = base + t * 4 + u;
        if (idx < N_NODES) {
            int v = offs[idx] + add;
            offs[idx] = v;
            cursor[idx] = v;
        }
    }
    if (b == 0 && t == 0) offs[N_NODES] = N_EDGES;
}

// fill: one packed 8B (src, w) store per edge
__global__ __launch_bounds__(256) void fill_kernel(
    const int* __restrict__ src, const int* __restrict__ dst,
    const float* __restrict__ w, int* __restrict__ cursor,
    int2* __restrict__ ep)
{
    int e = blockIdx.x * 256 + threadIdx.x;
    if (e >= N_EDGES) return;
    int d = dst[e];
    int p = atomicAdd(&cursor[d], 1);
    ep[p] = make_int2(src[e], __float_as_int(w[e]));
}

// ---------------------------------------------------------------------------
// Dense kernels: ONE THREAD PER NODE, NO LDS. All weight reads are at
// thread-uniform addresses -> compiler emits scalar (s_load) accesses and
// v_fma with SGPR operands. Zero LDS traffic, zero bank conflicts.
// Occupancy is grid-limited (391 blocks); long independent FMA chains give
// the ILP to stay VALU-issue-bound.
// ---------------------------------------------------------------------------

// Kernel A: encoder + LN(layer0) + dual GEMM(layer0)
__global__ __launch_bounds__(256) void enc_ln_gemm(
    const float* __restrict__ x,
    const float* __restrict__ W1, const float* __restrict__ b1,
    const float* __restrict__ W2, const float* __restrict__ b2,
    const float* __restrict__ ln_g, const float* __restrict__ ln_b,
    const float* __restrict__ nodeW, const float* __restrict__ node_b,
    const float* __restrict__ edgeW, const float* __restrict__ edge_b,
    float* __restrict__ H, float* __restrict__ Y, float* __restrict__ Z)
{
    int n = blockIdx.x * 256 + threadIdx.x;
    if (n >= N_NODES) return;

    float xi[16];
    const float4* xv = (const float4*)(x + (size_t)n * 16);
    #pragma unroll
    for (int i = 0; i < 4; i++) {
        float4 t = xv[i];
        xi[4 * i] = t.x; xi[4 * i + 1] = t.y; xi[4 * i + 2] = t.z; xi[4 * i + 3] = t.w;
    }

    float h[64];
    #pragma unroll
    for (int j = 0; j < 64; j++) h[j] = b2[j];

    #pragma unroll 4
    for (int k = 0; k < 128; k++) {
        float t = b1[k];
        #pragma unroll
        for (int i = 0; i < 16; i++) t += xi[i] * W1[i * 128 + k];
        t = leaky(t);
        #pragma unroll
        for (int j = 0; j < 64; j++) h[j] += t * W2[k * 64 + j];
    }

    // LN
    float s = 0.f, s2 = 0.f;
    #pragma unroll
    for (int j = 0; j < 64; j++) { s += h[j]; s2 += h[j] * h[j]; }
    float mu  = s * (1.f / 64.f);
    float var = s2 * (1.f / 64.f) - mu * mu;
    float rs  = rsqrtf(var + 1e-5f);
    #pragma unroll
    for (int j = 0; j < 64; j++)
        h[j] = (h[j] - mu) * rs * ln_g[j] + ln_b[j];

    float4* hs = (float4*)(H + (size_t)n * 64);
    #pragma unroll
    for (int c = 0; c < 16; c++)
        hs[c] = make_float4(h[4 * c], h[4 * c + 1], h[4 * c + 2], h[4 * c + 3]);

    // dual GEMM
    float aY[32], aZ[32];
    #pragma unroll
    for (int j = 0; j < 32; j++) { aY[j] = node_b[j] + edge_b[j]; aZ[j] = 0.f; }
    #pragma unroll 4
    for (int k = 0; k < 64; k++) {
        float v = h[k];
        #pragma unroll
        for (int j = 0; j < 32; j++) aY[j] += v * nodeW[k * 32 + j];
        #pragma unroll
        for (int j = 0; j < 32; j++) aZ[j] += v * edgeW[k * 32 + j];
    }
    float4* yv = (float4*)(Y + (size_t)n * 32);
    float4* zv = (float4*)(Z + (size_t)n * 32);
    #pragma unroll
    for (int c = 0; c < 8; c++) {
        yv[c] = make_float4(aY[4 * c], aY[4 * c + 1], aY[4 * c + 2], aY[4 * c + 3]);
        zv[c] = make_float4(aZ[4 * c], aZ[4 * c + 1], aZ[4 * c + 2], aZ[4 * c + 3]);
    }
}

// ---------------------------------------------------------------------------
// Gather: Y[n] += sum over incoming edges of w_e * Z[src_e]  (8 lanes/node)
// ---------------------------------------------------------------------------
__global__ __launch_bounds__(256) void gather_kernel(
    const int* __restrict__ offs, const int2* __restrict__ ep,
    const float* __restrict__ Z, float* __restrict__ Y)
{
    int gid = blockIdx.x * 256 + threadIdx.x;
    int node = gid >> 3;
    int lane = gid & 7;
    if (node >= N_NODES) return;
    int p0 = offs[node], p1 = offs[node + 1];
    float4 acc = make_float4(0.f, 0.f, 0.f, 0.f);
    for (int p = p0; p < p1; p++) {
        int2 pr = ep[p];
        float we = __int_as_float(pr.y);
        float4 zv = ((const float4*)Z)[(size_t)pr.x * 8 + lane];
        acc.x += we * zv.x; acc.y += we * zv.y;
        acc.z += we * zv.z; acc.w += we * zv.w;
    }
    float4* yp = (float4*)(Y + (size_t)node * 32) + lane;
    float4 y = *yp;
    y.x += acc.x; y.y += acc.y; y.z += acc.z; y.w += acc.w;
    *yp = y;
}

// ---------------------------------------------------------------------------
// Kernel B: mlp+residual (layer l) then LN + dual GEMM (layer l+1)
// ---------------------------------------------------------------------------
__global__ __launch_bounds__(256) void mlp_ln_gemm(
    float* __restrict__ Yio, float* __restrict__ H, float* __restrict__ Z,
    const float* __restrict__ mlpW, const float* __restrict__ mlp_b,
    const float* __restrict__ ln_g, const float* __restrict__ ln_b,
    const float* __restrict__ nodeW, const float* __restrict__ node_b,
    const float* __restrict__ edgeW, const float* __restrict__ edge_b)
{
    int n = blockIdx.x * 256 + threadIdx.x;
    if (n >= N_NODES) return;

    float ly[32];
    const float4* yvin = (const float4*)(Yio + (size_t)n * 32);
    #pragma unroll
    for (int i = 0; i < 8; i++) {
        float4 t = yvin[i];
        ly[4 * i] = leaky(t.x); ly[4 * i + 1] = leaky(t.y);
        ly[4 * i + 2] = leaky(t.z); ly[4 * i + 3] = leaky(t.w);
    }

    float h[64];
    #pragma unroll
    for (int j = 0; j < 64; j++) h[j] = mlp_b[j];
    #pragma unroll 4
    for (int k = 0; k < 32; k++) {
        float v = ly[k];
        #pragma unroll
        for (int j = 0; j < 64; j++) h[j] += v * mlpW[k * 64 + j];
    }

    // residual
    float4* hp = (float4*)(H + (size_t)n * 64);
    #pragma unroll
    for (int c = 0; c < 16; c++) {
        float4 r = hp[c];
        h[4 * c] += r.x; h[4 * c + 1] += r.y; h[4 * c + 2] += r.z; h[4 * c + 3] += r.w;
    }

    // LN
    float s = 0.f, s2 = 0.f;
    #pragma unroll
    for (int j = 0; j < 64; j++) { s += h[j]; s2 += h[j] * h[j]; }
    float mu  = s * (1.f / 64.f);
    float var = s2 * (1.f / 64.f) - mu * mu;
    float rs  = rsqrtf(var + 1e-5f);
    #pragma unroll
    for (int j = 0; j < 64; j++)
        h[j] = (h[j] - mu) * rs * ln_g[j] + ln_b[j];

    #pragma unroll
    for (int c = 0; c < 16; c++)
        hp[c] = make_float4(h[4 * c], h[4 * c + 1], h[4 * c + 2], h[4 * c + 3]);

    // dual GEMM
    float aY[32], aZ[32];
    #pragma unroll
    for (int j = 0; j < 32; j++) { aY[j] = node_b[j] + edge_b[j]; aZ[j] = 0.f; }
    #pragma unroll 4
    for (int k = 0; k < 64; k++) {
        float v = h[k];
        #pragma unroll
        for (int j = 0; j < 32; j++) aY[j] += v * nodeW[k * 32 + j];
        #pragma unroll
        for (int j = 0; j < 32; j++) aZ[j] += v * edgeW[k * 32 + j];
    }
    float4* yo = (float4*)(Yio + (size_t)n * 32);
    float4* zv = (float4*)(Z + (size_t)n * 32);
    #pragma unroll
    for (int c = 0; c < 8; c++) {
        yo[c] = make_float4(aY[4 * c], aY[4 * c + 1], aY[4 * c + 2], aY[4 * c + 3]);
        zv[c] = make_float4(aZ[4 * c], aZ[4 * c + 1], aZ[4 * c + 2], aZ[4 * c + 3]);
    }
}

// ---------------------------------------------------------------------------
// Kernel C: mlp+residual (layer 3) then decoder
// ---------------------------------------------------------------------------
__global__ __launch_bounds__(256) void mlp_dec(
    const float* __restrict__ Y, const float* __restrict__ H,
    const float* __restrict__ mlpW, const float* __restrict__ mlp_b,
    const float* __restrict__ dW1, const float* __restrict__ db1,
    const float* __restrict__ dW2, const float* __restrict__ db2,
    float* __restrict__ out)
{
    int n = blockIdx.x * 256 + threadIdx.x;
    if (n >= N_NODES) return;

    float ly[32];
    const float4* yvin = (const float4*)(Y + (size_t)n * 32);
    #pragma unroll
    for (int i = 0; i < 8; i++) {
        float4 t = yvin[i];
        ly[4 * i] = leaky(t.x); ly[4 * i + 1] = leaky(t.y);
        ly[4 * i + 2] = leaky(t.z); ly[4 * i + 3] = leaky(t.w);
    }

    float h[64];
    #pragma unroll
    for (int j = 0; j < 64; j++) h[j] = mlp_b[j];
    #pragma unroll 4
    for (int k = 0; k < 32; k++) {
        float v = ly[k];
        #pragma unroll
        for (int j = 0; j < 64; j++) h[j] += v * mlpW[k * 64 + j];
    }
    const float4* hp = (const float4*)(H + (size_t)n * 64);
    #pragma unroll
    for (int c = 0; c < 16; c++) {
        float4 r = hp[c];
        h[4 * c] += r.x; h[4 * c + 1] += r.y; h[4 * c + 2] += r.z; h[4 * c + 3] += r.w;
    }

    // decoder
    float hid[24];
    #pragma unroll
    for (int t = 0; t < 24; t++) hid[t] = db1[t];
    #pragma unroll 4
    for (int k = 0; k < 64; k++) {
        float v = h[k];
        #pragma unroll
        for (int t = 0; t < 24; t++) hid[t] += v * dW1[k * 24 + t];
    }
    float o0 = db2[0], o1 = db2[1], o2 = db2[2];
    #pragma unroll
    for (int t = 0; t < 24; t++) {
        float lt = leaky(hid[t]);
        o0 += lt * dW2[t * 3 + 0];
        o1 += lt * dW2[t * 3 + 1];
        o2 += lt * dW2[t * 3 + 2];
    }
    float* op = out + (size_t)n * 3;
    op[0] = o0; op[1] = o1; op[2] = o2;
}

// ---------------------------------------------------------------------------
extern "C" void kernel_launch(void* const* d_in, const int* in_sizes, int n_in,
                              void* d_out, int out_size, void* d_ws, size_t ws_size,
                              hipStream_t stream)
{
    const float* x      = (const float*)d_in[0];
    const int*   esrc   = (const int*)d_in[2];
    const int*   edst   = (const int*)d_in[3];
    const float* ew     = (const float*)d_in[4];
    const float* enc_W1 = (const float*)d_in[5];
    const float* enc_b1 = (const float*)d_in[6];
    const float* enc_W2 = (const float*)d_in[7];
    const float* enc_b2 = (const float*)d_in[8];
    const float* dec_W1 = (const float*)d_in[9];
    const float* dec_b1 = (const float*)d_in[10];
    const float* dec_W2 = (const float*)d_in[11];
    const float* dec_b2 = (const float*)d_in[12];
    const float* ln_g   = (const float*)d_in[13];
    const float* ln_b   = (const float*)d_in[14];
    const float* node_W = (const float*)d_in[15];
    const float* node_b = (const float*)d_in[16];
    const float* edge_W = (const float*)d_in[17];
    const float* edge_b = (const float*)d_in[18];
    const float* mlp_W  = (const float*)d_in[19];
    const float* mlp_b  = (const float*)d_in[20];

    // Workspace: floats H[N*64] | Y[N*32] | Z[N*32] | ep[E int2]
    //            ints counts[N] | offs[N+1] | cursor[N] | bsum | bscan
    float* H  = (float*)d_ws;
    float* Y  = H + (size_t)N_NODES * 64;
    float* Z  = Y + (size_t)N_NODES * 32;
    int2*  ep = (int2*)(Z + (size_t)N_NODES * 32);
    int* counts = (int*)(ep + N_EDGES);
    int* offs   = counts + N_NODES;          // N_NODES+1 entries
    int* cursor = offs + N_NODES + 1;
    int* bsum   = cursor + N_NODES;
    int* bscan  = bsum + NB1;

    const int nodeBlocks   = (N_NODES + 255) / 256;
    const int edgeBlocks   = (N_EDGES + 255) / 256;
    const int gatherBlocks = (N_NODES * 8 + 255) / 256;

    // --- CSR build (counting sort by dst) ---
    zero_counts<<<nodeBlocks, 256, 0, stream>>>(counts);
    count_kernel<<<edgeBlocks, 256, 0, stream>>>(edst, counts);
    scan1_kernel<<<NB1, 256, 0, stream>>>(counts, offs, bsum);
    scan2_kernel<<<1, 128, 0, stream>>>(bsum, bscan);
    scan3_kernel<<<NB1, 256, 0, stream>>>(offs, cursor, bscan);
    fill_kernel<<<edgeBlocks, 256, 0, stream>>>(esrc, edst, ew, cursor, ep);

    // --- network ---
    enc_ln_gemm<<<nodeBlocks, 256, 0, stream>>>(
        x, enc_W1, enc_b1, enc_W2, enc_b2,
        ln_g, ln_b, node_W, node_b, edge_W, edge_b, H, Y, Z);

    for (int l = 0; l < LAYERS - 1; l++) {
        gather_kernel<<<gatherBlocks, 256, 0, stream>>>(offs, ep, Z, Y);
        mlp_ln_gemm<<<nodeBlocks, 256, 0, stream>>>(
            Y, H, Z,
            mlp_W + l * 32 * 64, mlp_b + l * 64,
            ln_g + (l + 1) * 64, ln_b + (l + 1) * 64,
            node_W + (l + 1) * 64 * 32, node_b + (l + 1) * 32,
            edge_W + (l + 1) * 64 * 32, edge_b + (l + 1) * 32);
    }
    gather_kernel<<<gatherBlocks, 256, 0, stream>>>(offs, ep, Z, Y);
    mlp_dec<<<nodeBlocks, 256, 0, stream>>>(
        Y, H, mlp_W + 3 * 32 * 64, mlp_b + 3 * 64,
        dec_W1, dec_b1, dec_W2, dec_b2, (float*)d_out);
}